// Round 1
// 218.759 us; speedup vs baseline: 1.4606x; 1.4606x over previous
//
#include <hip/hip_runtime.h>
#include <hip/hip_bf16.h>

typedef _Float16 half8 __attribute__((ext_vector_type(8)));
typedef _Float16 half4 __attribute__((ext_vector_type(4)));
typedef float floatx16 __attribute__((ext_vector_type(16)));
typedef float float4v __attribute__((ext_vector_type(4)));

#define BATCH 32768
#define TT 30

// fast hw transcendentals (1-2 ulp): v_exp_f32 is exp2, v_rcp_f32 is rcp
#if __has_builtin(__builtin_amdgcn_exp2f)
#define FEXP2(x) __builtin_amdgcn_exp2f(x)
#else
#define FEXP2(x) __expf((x) * 0.6931471805599453f)
#endif
#if __has_builtin(__builtin_amdgcn_rcpf)
#define FRCP(x) __builtin_amdgcn_rcpf(x)
#else
#define FRCP(x) (1.0f / (x))
#endif

#define NLOG2E  -1.4426950408889634f
#define N2LOG2E -2.8853900817779268f

// ws offsets (in floats) — layout unchanged; gate weights/biases PRESCALED:
// gates i,f,o by -log2e, gate g by -2*log2e, so sigma = rcp(1+exp2(acc)).
#define WFRAG_OFF 0        // f16[8 tiles][5 ks][64 lane][8] = 20480 halves
#define WCF_OFF   10240    // f16[2 waves][4 ks][64 lane][8] = 4096 halves
#define BIASB_OFF 12288    // f32[256]  (b_ih + b_hh) * gate_scale
#define SXY_OFF   12544    // f32[16][3]   (Sx, Sy, bse)
#define CBIAS_OFF 12592    // f32[2][32]   (w0: bpos|0, w1: bx=bse+Wse*bpos|0)
#define WCONF_OFF 12656    // f32[384]
#define BCONF_OFF 13040    // f32[6]
#define FLAG_IDX  13056    // int: 1 => inputs fp32, 0 => bf16
#define CONF_BASE (BATCH * 360)

__global__ void detect_kernel(const unsigned short* __restrict__ raw,
                              int* __restrict__ flag_out) {
    __shared__ int sflag[256];
    int local = 0;
    for (int i = threadIdx.x; i < 16384; i += 256) {
        unsigned short u = raw[i];
        if ((u & 0x7F80u) == 0x7F80u) local = 1;
    }
    sflag[threadIdx.x] = local;
    __syncthreads();
    if (threadIdx.x == 0) {
        int f = 0;
        for (int i = 0; i < 256; ++i) f |= sflag[i];
        flag_out[0] = f;
    }
}

__device__ __forceinline__ float ldin(const void* p, int i, int isf32) {
    return isf32 ? ((const float*)p)[i]
                 : (float)((const __hip_bfloat16*)p)[i];
}

__global__ void prep_kernel(const void* __restrict__ W_ih,
                            const void* __restrict__ W_hh,
                            const void* __restrict__ b_ih,
                            const void* __restrict__ b_hh,
                            const void* __restrict__ W_se,
                            const void* __restrict__ b_se,
                            const void* __restrict__ W_pos,
                            const void* __restrict__ b_pos,
                            const void* __restrict__ W_conf,
                            const void* __restrict__ b_conf,
                            float* __restrict__ ws)
{
    const int isf32 = ((const int*)(ws + FLAG_IDX))[0];
    int tid = blockIdx.x * blockDim.x + threadIdx.x;
    int stride = gridDim.x * blockDim.x;
    _Float16* wfh = (_Float16*)ws;

    // Gate-GEMM B fragments: tile tl=(gate*2+ug); B[k][n]: n=lane&31 (unit
    // j=ug*32+n), k = ks*16 + (lane>>5)*8 + jj.  PRESCALED by gate scale so
    // the activation needs no multiply before v_exp.
    for (int idx = tid; idx < 20480; idx += stride) {
        int tl = idx / 2560, r1 = idx % 2560;
        int ks = r1 / 512, r2 = r1 % 512;
        int lane = r2 >> 3, jj = r2 & 7;
        int gate = tl >> 1, ug = tl & 1;
        int k = ks * 16 + (lane >> 5) * 8 + jj;
        int jn = ug * 32 + (lane & 31);
        int row = gate * 64 + jn;
        float v = (k < 16) ? ldin(W_ih, row * 16 + k, isf32)
                           : ldin(W_hh, row * 64 + (k - 16), isf32);
        v *= (gate == 2) ? N2LOG2E : NLOG2E;
        wfh[idx] = (_Float16)v;
    }
    // Fused C-GEMM fragments (unscaled: rel/x are linear outputs).
    _Float16* wch = (_Float16*)(ws + WCF_OFF);
    for (int idx = tid; idx < 4096; idx += stride) {
        int w = idx >> 11, r1 = idx & 2047;
        int ks = r1 >> 9, r2 = r1 & 511;
        int lane = r2 >> 3, jj = r2 & 7;
        int n = lane & 31;
        int krel = ks * 16 + (lane >> 5) * 8 + jj;
        float v = 0.f;
        if (w == 0) {
            if (n < 12) v = ldin(W_pos, n * 64 + krel, isf32);
        } else if (n < 16) {
            float s = 0.f;
            for (int p = 0; p < 12; ++p)
                s += ldin(W_se, n * 12 + p, isf32) * ldin(W_pos, p * 64 + krel, isf32);
            v = s;
        }
        wch[idx] = (_Float16)v;
    }
    for (int idx = tid; idx < 256; idx += stride) {
        int gate = idx >> 6;
        float scale = (gate == 2) ? N2LOG2E : NLOG2E;
        ws[BIASB_OFF + idx] = (ldin(b_ih, idx, isf32) + ldin(b_hh, idx, isf32)) * scale;
    }
    for (int idx = tid; idx < 16; idx += stride) {
        float sx = 0.f, sy = 0.f;
        for (int m = 0; m < 6; ++m) {
            sx += ldin(W_se, idx * 12 + 2 * m, isf32);
            sy += ldin(W_se, idx * 12 + 2 * m + 1, isf32);
        }
        ws[SXY_OFF + idx * 3 + 0] = sx;
        ws[SXY_OFF + idx * 3 + 1] = sy;
        ws[SXY_OFF + idx * 3 + 2] = ldin(b_se, idx, isf32);
    }
    for (int idx = tid; idx < 64; idx += stride) {
        int w = idx >> 5, cc = idx & 31;
        float v = 0.f;
        if (w == 0) {
            if (cc < 12) v = ldin(b_pos, cc, isf32);
        } else if (cc < 16) {
            float s = ldin(b_se, cc, isf32);
            for (int p = 0; p < 12; ++p)
                s += ldin(W_se, cc * 12 + p, isf32) * ldin(b_pos, p, isf32);
            v = s;
        }
        ws[CBIAS_OFF + idx] = v;
    }
    for (int idx = tid; idx < 384; idx += stride)
        ws[WCONF_OFF + idx] = ldin(W_conf, idx, isf32);
    for (int idx = tid; idx < 6; idx += stride)
        ws[BCONF_OFF + idx] = ldin(b_conf, idx, isf32);
}

// block = 128 thr = 2 waves; 32 agents/block. zT now lives in LDS as f16
// (the MFMA consumes f16 anyway) -> ds_read_b128 feeds A-frags directly,
// deleting 72 v_cvt per thread-step.  Activations use v_exp_f32/v_rcp_f32
// with prescaled gate weights: sigma=rcp(1+exp2(acc)) (3 instrs vs ~14 for
// the IEEE-division version).  3 barriers/step, pred buffered f16 in LDS,
// single coalesced float4 flush at the end.
__global__ __launch_bounds__(128, 2) void lstm_kernel(
    const void* __restrict__ traj_rel,
    const void* __restrict__ h0,
    const void* __restrict__ c0,
    const float* __restrict__ ws,
    float* __restrict__ out)
{
    __shared__ _Float16 zsh[32 * 88];        // [agent r][k: 0..15 x | 16..79 h | pad]
    __shared__ _Float16 predh[12 * 30 * 36]; // pb[p=m*2+xy][t][36]

    const int tid = threadIdx.x;
    const int lane = tid & 63;
    const int ug = __builtin_amdgcn_readfirstlane(tid >> 6);  // wave id 0/1
    const int col = lane & 31;
    const int half = lane >> 5;
    const int j = ug * 32 + col;
    const int base = blockIdx.x * 32;
    const int isf32 = ((const int*)(ws + FLAG_IDX))[0];

    // ---- per-lane constants ----
    const float4v* wfg = (const float4v*)ws;
    half8 Bf[4][5];
#pragma unroll
    for (int g = 0; g < 4; ++g)
#pragma unroll
        for (int ks = 0; ks < 5; ++ks)
            Bf[g][ks] = __builtin_bit_cast(half8,
                wfg[((g * 2 + ug) * 5 + ks) * 64 + lane]);
    float bias4[4];
#pragma unroll
    for (int g = 0; g < 4; ++g) bias4[g] = ws[BIASB_OFF + g * 64 + j];

    half8 wfc[4];
    {
        const float4v* wcg = (const float4v*)(ws + WCF_OFF);
#pragma unroll
        for (int ks = 0; ks < 4; ++ks)
            wfc[ks] = __builtin_bit_cast(half8, wcg[(ug * 4 + ks) * 64 + lane]);
    }
    const float cb = ws[CBIAS_OFF + ug * 32 + col];

    // ---- init: c in regs (C-layout rows), h0 -> zT (f16), x0 -> zT ----
    float c[16];
#pragma unroll
    for (int i = 0; i < 16; ++i) {
        int r = (i & 3) + 8 * (i >> 2) + 4 * half;
        c[i] = ldin(c0, (base + r) * 64 + j, isf32);
    }
    {   // h0: thread t -> (m = t&31, jq = t>>5), 16 cols -> f16
        int m = tid & 31, jq = tid >> 5;
        half8 ha, hb;
#pragma unroll
        for (int i = 0; i < 8; ++i)
            ha[i] = (_Float16)ldin(h0, (base + m) * 64 + jq * 16 + i, isf32);
#pragma unroll
        for (int i = 0; i < 8; ++i)
            hb[i] = (_Float16)ldin(h0, (base + m) * 64 + jq * 16 + 8 + i, isf32);
        *(half8*)&zsh[m * 88 + 16 + jq * 16] = ha;
        *(half8*)&zsh[m * 88 + 16 + jq * 16 + 8] = hb;
        // x0 = lrelu(rx*Sx + ry*Sy + bse); thread covers e = 4*jq..+4
        float rx = ldin(traj_rel, 2 * (base + m), isf32);
        float ry = ldin(traj_rel, 2 * (base + m) + 1, isf32);
        half4 xs;
#pragma unroll
        for (int i = 0; i < 4; ++i) {
            int e = 4 * jq + i;
            float x = fmaf(rx, ws[SXY_OFF + e * 3],
                      fmaf(ry, ws[SXY_OFF + e * 3 + 1], ws[SXY_OFF + e * 3 + 2]));
            xs[i] = (_Float16)(x > 0.f ? x : 0.01f * x);
        }
        *(half4*)&zsh[m * 88 + 4 * jq] = xs;
    }
    __syncthreads();

    const int zb = col * 88 + half * 8;

    for (int t = 0; t < TT; ++t) {
        // ---- A: gates = z @ Wcat^T + bias (MFMA), A-frags straight from f16 LDS ----
        floatx16 acc[4];
#pragma unroll
        for (int g = 0; g < 4; ++g)
#pragma unroll
            for (int i = 0; i < 16; ++i) acc[g][i] = bias4[g];
#pragma unroll
        for (int ks = 0; ks < 5; ++ks) {
            half8 af = *(const half8*)&zsh[zb + ks * 16];
#pragma unroll
            for (int g = 0; g < 4; ++g)
                acc[g] = __builtin_amdgcn_mfma_f32_32x32x16_f16(af, Bf[g][ks], acc[g], 0, 0, 0);
        }
        __syncthreads();  // bar0: A-reads done before h overwrite

        // ---- B: activations (v_exp/v_rcp) + c update, write h -> zT (f16) ----
#pragma unroll
        for (int i = 0; i < 16; ++i) {
            float si = FRCP(1.0f + FEXP2(acc[0][i]));
            float sf = FRCP(1.0f + FEXP2(acc[1][i]));
            float tg = fmaf(2.0f, FRCP(1.0f + FEXP2(acc[2][i])), -1.0f);
            float so = FRCP(1.0f + FEXP2(acc[3][i]));
            float cn = fmaf(sf, c[i], si * tg);
            c[i] = cn;
            float th = fmaf(2.0f, FRCP(1.0f + FEXP2(cn * N2LOG2E)), -1.0f);
            float hn = so * th;
            int r = (i & 3) + 8 * (i >> 2) + 4 * half;
            zsh[r * 88 + 16 + j] = (_Float16)hn;
        }
        __syncthreads();  // bar1: h complete

        // ---- C: fused (rel | x) = h @ [Wpos | M]^T + [bpos | bx] ----
        {
            floatx16 racc;
#pragma unroll
            for (int i = 0; i < 16; ++i) racc[i] = cb;
#pragma unroll
            for (int ks = 0; ks < 4; ++ks) {
                half8 af = *(const half8*)&zsh[zb + 16 + ks * 16];
                racc = __builtin_amdgcn_mfma_f32_32x32x16_f16(af, wfc[ks], racc, 0, 0, 0);
            }
            if (ug == 0) {
                if (col < 12) {
#pragma unroll
                    for (int q2 = 0; q2 < 4; ++q2) {
                        half4 hv;
#pragma unroll
                        for (int i = 0; i < 4; ++i) hv[i] = (_Float16)racc[q2 * 4 + i];
                        *(half4*)&predh[(col * 30 + t) * 36 + q2 * 8 + 4 * half] = hv;
                    }
                }
            } else if (t != TT - 1) {
                if (col < 16) {
#pragma unroll
                    for (int i = 0; i < 16; ++i) {
                        float xv = racc[i];
                        xv = xv > 0.f ? xv : 0.01f * xv;
                        int r = (i & 3) + 8 * (i >> 2) + 4 * half;
                        zsh[r * 88 + col] = (_Float16)xv;
                    }
                }
            }
        }
        __syncthreads();  // bar2: pred/x writes done; next A may read
    }

    // ---- single coalesced flush: predh -> out (float4 per thread-iter) ----
    {
        float4* po4 = (float4*)(out + (size_t)base * 360);
#pragma unroll 1
        for (int q2 = 0; q2 < 23; ++q2) {
            int idx4 = q2 * 128 + tid;
            if (idx4 < 2880) {
                int a = idx4 / 90, rem = idx4 % 90;
                int m = rem / 15, tq = rem % 15;
                int t0 = tq * 2;
                float4 o;
                o.x = (float)predh[((2 * m + 0) * 30 + t0) * 36 + a];
                o.y = (float)predh[((2 * m + 1) * 30 + t0) * 36 + a];
                o.z = (float)predh[((2 * m + 0) * 30 + t0 + 1) * 36 + a];
                o.w = (float)predh[((2 * m + 1) * 30 + t0 + 1) * 36 + a];
                po4[idx4] = o;
            }
        }
    }

    // ---- conf = softmax(h @ Wconf^T + bconf): wave 0, lanes 0..31 ----
    if (ug == 0 && half == 0) {
        int m = col;
        float l[6];
#pragma unroll
        for (int md = 0; md < 6; ++md) l[md] = ws[BCONF_OFF + md];
        for (int jj = 0; jj < 64; ++jj) {
            float hv = (float)zsh[m * 88 + 16 + jj];
#pragma unroll
            for (int md = 0; md < 6; ++md)
                l[md] = fmaf(hv, ws[WCONF_OFF + md * 64 + jj], l[md]);
        }
        float mx = l[0];
#pragma unroll
        for (int md = 1; md < 6; ++md) mx = fmaxf(mx, l[md]);
        float ex[6], s = 0.f;
#pragma unroll
        for (int md = 0; md < 6; ++md) { ex[md] = __expf(l[md] - mx); s += ex[md]; }
        float inv = FRCP(s);
#pragma unroll
        for (int md = 0; md < 6; ++md)
            out[CONF_BASE + (size_t)(base + m) * 6 + md] = ex[md] * inv;
    }
}

extern "C" void kernel_launch(void* const* d_in, const int* in_sizes, int n_in,
                              void* d_out, int out_size, void* d_ws, size_t ws_size,
                              hipStream_t stream) {
    const void* traj_rel = d_in[1];
    const void* h0   = d_in[2];
    const void* c0   = d_in[3];
    const void* W_ih = d_in[4];
    const void* W_hh = d_in[5];
    const void* b_ih = d_in[6];
    const void* b_hh = d_in[7];
    const void* W_se = d_in[8];
    const void* b_se = d_in[9];
    const void* W_pos  = d_in[10];
    const void* b_pos  = d_in[11];
    const void* W_conf = d_in[12];
    const void* b_conf = d_in[13];
    float* ws = (float*)d_ws;
    float* out = (float*)d_out;

    detect_kernel<<<1, 256, 0, stream>>>((const unsigned short*)W_hh,
                                         (int*)(ws + FLAG_IDX));
    prep_kernel<<<40, 256, 0, stream>>>(W_ih, W_hh, b_ih, b_hh, W_se, b_se,
                                        W_pos, b_pos, W_conf, b_conf, ws);
    lstm_kernel<<<BATCH / 32, 128, 0, stream>>>(traj_rel, h0, c0, ws, out);
}

// Round 2
// 208.451 us; speedup vs baseline: 1.5328x; 1.0494x over previous
//
#include <hip/hip_runtime.h>
#include <hip/hip_bf16.h>

typedef _Float16 half8 __attribute__((ext_vector_type(8)));
typedef _Float16 half4 __attribute__((ext_vector_type(4)));
typedef float float4v __attribute__((ext_vector_type(4)));

#define BATCH 32768
#define TT 30

#if __has_builtin(__builtin_amdgcn_exp2f)
#define FEXP2(x) __builtin_amdgcn_exp2f(x)
#else
#define FEXP2(x) __expf((x) * 0.6931471805599453f)
#endif
#if __has_builtin(__builtin_amdgcn_rcpf)
#define FRCP(x) __builtin_amdgcn_rcpf(x)
#else
#define FRCP(x) (1.0f / (x))
#endif

#define NLOG2E  -1.4426950408889634f
#define N2LOG2E -2.8853900817779268f

// ws offsets (floats). Gate weights/biases PRESCALED (-log2e; gate g -2log2e).
// 16x16x32 fragment layouts: A row=lane&15, k=(lane>>4)*8+j; B col=lane&15,
// same k; C/D col=lane&15, row=(lane>>4)*4+reg.
#define WFRAG_OFF 0        // f16[2 uh][8 tile][3 ks][64 lane][8] = 24576 halves
#define WCF_OFF   12288    // f16[2 uh][2 ks][64 lane][8] = 2048 halves
#define BIASB_OFF 13312    // f32[256]  (b_ih + b_hh) * gate_scale
#define SXY_OFF   13568    // f32[16][3]   (Sx, Sy, bse)
#define CBIAS_OFF 13616    // f32[2][16]   (uh0: bpos|0, uh1: bx)
#define WCONF_OFF 13648    // f32[384]
#define BCONF_OFF 14032    // f32[6]
#define FLAG_IDX  14038    // int: 1 => inputs fp32, 0 => bf16
#define CONF_BASE (BATCH * 360)

__global__ void detect_kernel(const unsigned short* __restrict__ raw,
                              int* __restrict__ flag_out) {
    __shared__ int sflag[256];
    int local = 0;
    for (int i = threadIdx.x; i < 16384; i += 256) {
        unsigned short u = raw[i];
        if ((u & 0x7F80u) == 0x7F80u) local = 1;
    }
    sflag[threadIdx.x] = local;
    __syncthreads();
    if (threadIdx.x == 0) {
        int f = 0;
        for (int i = 0; i < 256; ++i) f |= sflag[i];
        flag_out[0] = f;
    }
}

__device__ __forceinline__ float ldin(const void* p, int i, int isf32) {
    return isf32 ? ((const float*)p)[i]
                 : (float)((const __hip_bfloat16*)p)[i];
}

__global__ void prep_kernel(const void* __restrict__ W_ih,
                            const void* __restrict__ W_hh,
                            const void* __restrict__ b_ih,
                            const void* __restrict__ b_hh,
                            const void* __restrict__ W_se,
                            const void* __restrict__ b_se,
                            const void* __restrict__ W_pos,
                            const void* __restrict__ b_pos,
                            const void* __restrict__ W_conf,
                            const void* __restrict__ b_conf,
                            float* __restrict__ ws)
{
    const int isf32 = ((const int*)(ws + FLAG_IDX))[0];
    int tid = blockIdx.x * blockDim.x + threadIdx.x;
    int stride = gridDim.x * blockDim.x;
    _Float16* wfh = (_Float16*)ws;

    // Gate-GEMM B fragments, 16x16x32 tiles, K padded to 96 (k>=80 -> 0).
    // tile tl = gate*2+usub; unit = uh*32 + usub*16 + col.
    for (int idx = tid; idx < 24576; idx += stride) {
        int jj = idx & 7, r = idx >> 3;
        int lane = r & 63; r >>= 6;
        int ks = r % 3; r /= 3;
        int tl = r & 7; int uhh = r >> 3;
        int col = lane & 15, akq = lane >> 4;
        int k = ks * 32 + akq * 8 + jj;
        int gate = tl >> 1, us = tl & 1;
        int row = gate * 64 + uhh * 32 + us * 16 + col;
        float v = 0.f;
        if (k < 16) v = ldin(W_ih, row * 16 + k, isf32);
        else if (k < 80) v = ldin(W_hh, row * 64 + (k - 16), isf32);
        v *= (gate == 2) ? N2LOG2E : NLOG2E;
        wfh[idx] = (_Float16)v;
    }
    // Fused C-GEMM fragments: uh0 cols = Wpos (rel), uh1 cols = M=Wse*Wpos (x).
    _Float16* wch = (_Float16*)(ws + WCF_OFF);
    for (int idx = tid; idx < 2048; idx += stride) {
        int jj = idx & 7, r = idx >> 3;
        int lane = r & 63; r >>= 6;
        int ks = r & 1, uhh = r >> 1;
        int col = lane & 15, akq = lane >> 4;
        int k = ks * 32 + akq * 8 + jj;   // 0..63 over h
        float v = 0.f;
        if (uhh == 0) {
            if (col < 12) v = ldin(W_pos, col * 64 + k, isf32);
        } else {
            float s = 0.f;
            for (int p = 0; p < 12; ++p)
                s += ldin(W_se, col * 12 + p, isf32) * ldin(W_pos, p * 64 + k, isf32);
            v = s;
        }
        wch[idx] = (_Float16)v;
    }
    for (int idx = tid; idx < 256; idx += stride) {
        int gate = idx >> 6;
        float scale = (gate == 2) ? N2LOG2E : NLOG2E;
        ws[BIASB_OFF + idx] = (ldin(b_ih, idx, isf32) + ldin(b_hh, idx, isf32)) * scale;
    }
    for (int idx = tid; idx < 16; idx += stride) {
        float sx = 0.f, sy = 0.f;
        for (int m = 0; m < 6; ++m) {
            sx += ldin(W_se, idx * 12 + 2 * m, isf32);
            sy += ldin(W_se, idx * 12 + 2 * m + 1, isf32);
        }
        ws[SXY_OFF + idx * 3 + 0] = sx;
        ws[SXY_OFF + idx * 3 + 1] = sy;
        ws[SXY_OFF + idx * 3 + 2] = ldin(b_se, idx, isf32);
    }
    for (int idx = tid; idx < 32; idx += stride) {
        int w = idx >> 4, cc = idx & 15;
        float v = 0.f;
        if (w == 0) {
            if (cc < 12) v = ldin(b_pos, cc, isf32);
        } else {
            float s = ldin(b_se, cc, isf32);
            for (int p = 0; p < 12; ++p)
                s += ldin(W_se, cc * 12 + p, isf32) * ldin(b_pos, p, isf32);
            v = s;
        }
        ws[CBIAS_OFF + idx] = v;
    }
    for (int idx = tid; idx < 384; idx += stride)
        ws[WCONF_OFF + idx] = ldin(W_conf, idx, isf32);
    for (int idx = tid; idx < 6; idx += stride)
        ws[BCONF_OFF + idx] = ldin(b_conf, idx, isf32);
}

// block = 128 thr (2 waves), 32 agents split into two 16-agent groups running
// a phase-offset software pipeline so every inter-barrier slot mixes MFMA
// (one group) with transcendental activation work (the other group) in the
// SAME wave's instruction stream:
//   S1: A(G0,t) | C(G1,t-1)   -- bar
//   S2: A(G1,t) | B(G0,t)     -- bar
//   S3: C(G0,t) | B(G1,t)     -- bar
// Wave uh owns hidden units [32uh,32uh+32); C-phase: uh0 -> rel, uh1 -> x.
// zT per group: f16 [16 rows][104] (x16 | h64 | zero-pad16 | pad8).
__global__ __launch_bounds__(128, 2) void lstm_kernel(
    const void* __restrict__ traj_rel,
    const void* __restrict__ h0,
    const void* __restrict__ c0,
    const float* __restrict__ ws,
    float* __restrict__ out)
{
    __shared__ _Float16 zsh[2 * 16 * 104];
    __shared__ _Float16 predh[12 * 30 * 36];

    const int tid = threadIdx.x;
    const int lane = tid & 63;
    const int uh = __builtin_amdgcn_readfirstlane(tid >> 6);  // wave id 0/1
    const int col16 = lane & 15;
    const int akq = lane >> 4;          // 0..3
    const int base = blockIdx.x * 32;
    const int isf32 = ((const int*)(ws + FLAG_IDX))[0];

    // ---- per-lane constants ----
    const float4v* wfg = (const float4v*)ws;
    half8 Bf[8][3];
#pragma unroll
    for (int tl = 0; tl < 8; ++tl)
#pragma unroll
        for (int ks = 0; ks < 3; ++ks)
            Bf[tl][ks] = __builtin_bit_cast(half8,
                wfg[((uh * 8 + tl) * 3 + ks) * 64 + lane]);
    float bias8[8];
#pragma unroll
    for (int tl = 0; tl < 8; ++tl)
        bias8[tl] = ws[BIASB_OFF + (tl >> 1) * 64 + uh * 32 + (tl & 1) * 16 + col16];
    half8 wfc[2];
    {
        const float4v* wcg = (const float4v*)(ws + WCF_OFF);
#pragma unroll
        for (int ks = 0; ks < 2; ++ks)
            wfc[ks] = __builtin_bit_cast(half8, wcg[(uh * 2 + ks) * 64 + lane]);
    }
    const float cb = ws[CBIAS_OFF + uh * 16 + col16];

    // ---- init c (per group) ----
    float cg0[8], cg1[8];
#pragma unroll
    for (int us = 0; us < 2; ++us)
#pragma unroll
        for (int i = 0; i < 4; ++i) {
            int unit = uh * 32 + us * 16 + col16;
            cg0[us * 4 + i] = ldin(c0, (base + akq * 4 + i) * 64 + unit, isf32);
            cg1[us * 4 + i] = ldin(c0, (base + 16 + akq * 4 + i) * 64 + unit, isf32);
        }
    // ---- init zT: h0, x0, zero-pad ----
    {
        int m = tid & 31, jq = tid >> 5;   // agent-in-block, col quarter
        int g = m >> 4, row = m & 15;
        _Float16* zg = &zsh[g * 1664];
        half8 ha, hb;
#pragma unroll
        for (int i = 0; i < 8; ++i)
            ha[i] = (_Float16)ldin(h0, (base + m) * 64 + jq * 16 + i, isf32);
#pragma unroll
        for (int i = 0; i < 8; ++i)
            hb[i] = (_Float16)ldin(h0, (base + m) * 64 + jq * 16 + 8 + i, isf32);
        *(half8*)&zg[row * 104 + 16 + jq * 16] = ha;
        *(half8*)&zg[row * 104 + 16 + jq * 16 + 8] = hb;
        float rx = ldin(traj_rel, 2 * (base + m), isf32);
        float ry = ldin(traj_rel, 2 * (base + m) + 1, isf32);
        half4 xs;
#pragma unroll
        for (int i = 0; i < 4; ++i) {
            int e = 4 * jq + i;
            float x = fmaf(rx, ws[SXY_OFF + e * 3],
                      fmaf(ry, ws[SXY_OFF + e * 3 + 1], ws[SXY_OFF + e * 3 + 2]));
            xs[i] = (_Float16)(x > 0.f ? x : 0.01f * x);
        }
        *(half4*)&zg[row * 104 + 4 * jq] = xs;
        if (jq == 0) {   // zero-pad k = 80..95
            half8 zz = {};
            *(half8*)&zg[row * 104 + 80] = zz;
            *(half8*)&zg[row * 104 + 88] = zz;
        }
    }
    __syncthreads();

    const int zbA = col16 * 104 + akq * 8;
    const int zbC = zbA + 16;
    const int hwb = 16 + uh * 32 + col16;   // h-write base (+us*16)

    float4v acc0[8], acc1[8];

#define ZG(g) (&zsh[(g) * 1664])

#define PHASE_A(G, ACC) do {                                                  \
    _Float16* zg_ = ZG(G);                                                    \
    _Pragma("unroll")                                                         \
    for (int tl = 0; tl < 8; ++tl) {                                          \
        float bv = bias8[tl];                                                 \
        ACC[tl][0] = bv; ACC[tl][1] = bv; ACC[tl][2] = bv; ACC[tl][3] = bv;   \
    }                                                                         \
    _Pragma("unroll")                                                         \
    for (int ks = 0; ks < 3; ++ks) {                                          \
        half8 af_ = *(const half8*)&zg_[zbA + ks * 32];                       \
        _Pragma("unroll")                                                     \
        for (int tl = 0; tl < 8; ++tl)                                        \
            ACC[tl] = __builtin_amdgcn_mfma_f32_16x16x32_f16(                 \
                af_, Bf[tl][ks], ACC[tl], 0, 0, 0);                           \
    }                                                                         \
} while (0)

#define PHASE_B(G, ACC, CARR) do {                                            \
    _Float16* zg_ = ZG(G);                                                    \
    _Pragma("unroll")                                                         \
    for (int us = 0; us < 2; ++us) {                                          \
        _Pragma("unroll")                                                     \
        for (int i = 0; i < 4; ++i) {                                         \
            float si = FRCP(1.0f + FEXP2(ACC[us][i]));                        \
            float sf = FRCP(1.0f + FEXP2(ACC[2 + us][i]));                    \
            float tg = fmaf(2.0f, FRCP(1.0f + FEXP2(ACC[4 + us][i])), -1.0f); \
            float so = FRCP(1.0f + FEXP2(ACC[6 + us][i]));                    \
            float cn = fmaf(sf, CARR[us * 4 + i], si * tg);                   \
            CARR[us * 4 + i] = cn;                                            \
            float th = fmaf(2.0f, FRCP(1.0f + FEXP2(cn * N2LOG2E)), -1.0f);   \
            float hn = so * th;                                               \
            zg_[(akq * 4 + i) * 104 + hwb + us * 16] = (_Float16)hn;          \
        }                                                                     \
    }                                                                         \
} while (0)

// gate tiles: tl = gate*2+us -> i:us, f:2+us, g:4+us, o:6+us

#define PHASE_C(G, T) do {                                                    \
    _Float16* zg_ = ZG(G);                                                    \
    float4v racc_;                                                            \
    racc_[0] = cb; racc_[1] = cb; racc_[2] = cb; racc_[3] = cb;               \
    _Pragma("unroll")                                                         \
    for (int ks = 0; ks < 2; ++ks) {                                          \
        half8 af_ = *(const half8*)&zg_[zbC + ks * 32];                       \
        racc_ = __builtin_amdgcn_mfma_f32_16x16x32_f16(                       \
            af_, wfc[ks], racc_, 0, 0, 0);                                    \
    }                                                                         \
    if (uh == 0) {                                                            \
        if (col16 < 12) {                                                     \
            half4 hv_;                                                        \
            _Pragma("unroll")                                                 \
            for (int i = 0; i < 4; ++i) hv_[i] = (_Float16)racc_[i];          \
            *(half4*)&predh[(col16 * 30 + (T)) * 36 + (G) * 16 + akq * 4] = hv_; \
        }                                                                     \
    } else if ((T) != TT - 1) {                                               \
        _Pragma("unroll")                                                     \
        for (int i = 0; i < 4; ++i) {                                         \
            float xv_ = racc_[i];                                             \
            xv_ = xv_ > 0.f ? xv_ : 0.01f * xv_;                              \
            zg_[(akq * 4 + i) * 104 + col16] = (_Float16)xv_;                 \
        }                                                                     \
    }                                                                         \
} while (0)

    // ---- prologue (t = 0) ----
    PHASE_A(0, acc0);                       // S1
    __syncthreads();
    PHASE_A(1, acc1); PHASE_B(0, acc0, cg0);   // S2
    __syncthreads();
    PHASE_C(0, 0);    PHASE_B(1, acc1, cg1);   // S3
    __syncthreads();

    for (int t = 1; t < TT; ++t) {
        PHASE_A(0, acc0); PHASE_C(1, t - 1);      // S1
        __syncthreads();
        PHASE_A(1, acc1); PHASE_B(0, acc0, cg0);  // S2
        __syncthreads();
        PHASE_C(0, t);    PHASE_B(1, acc1, cg1);  // S3
        __syncthreads();
    }
    PHASE_C(1, TT - 1);                     // epilogue
    __syncthreads();

    // ---- single coalesced flush: predh -> out ----
    {
        float4* po4 = (float4*)(out + (size_t)base * 360);
#pragma unroll 1
        for (int q2 = 0; q2 < 23; ++q2) {
            int idx4 = q2 * 128 + tid;
            if (idx4 < 2880) {
                int a = idx4 / 90, rem = idx4 % 90;
                int m = rem / 15, tq = rem % 15;
                int t0 = tq * 2;
                float4 o;
                o.x = (float)predh[((2 * m + 0) * 30 + t0) * 36 + a];
                o.y = (float)predh[((2 * m + 1) * 30 + t0) * 36 + a];
                o.z = (float)predh[((2 * m + 0) * 30 + t0 + 1) * 36 + a];
                o.w = (float)predh[((2 * m + 1) * 30 + t0 + 1) * 36 + a];
                po4[idx4] = o;
            }
        }
    }

    // ---- conf = softmax(h @ Wconf^T + bconf): wave 0, lanes 0..31 ----
    if (uh == 0 && lane < 32) {
        int m = lane;
        int g = m >> 4, row = m & 15;
        float l[6];
#pragma unroll
        for (int md = 0; md < 6; ++md) l[md] = ws[BCONF_OFF + md];
        for (int jj = 0; jj < 64; ++jj) {
            float hv = (float)zsh[g * 1664 + row * 104 + 16 + jj];
#pragma unroll
            for (int md = 0; md < 6; ++md)
                l[md] = fmaf(hv, ws[WCONF_OFF + md * 64 + jj], l[md]);
        }
        float mx = l[0];
#pragma unroll
        for (int md = 1; md < 6; ++md) mx = fmaxf(mx, l[md]);
        float ex[6], s = 0.f;
#pragma unroll
        for (int md = 0; md < 6; ++md) { ex[md] = __expf(l[md] - mx); s += ex[md]; }
        float inv = FRCP(s);
#pragma unroll
        for (int md = 0; md < 6; ++md)
            out[CONF_BASE + (size_t)(base + m) * 6 + md] = ex[md] * inv;
    }
}

extern "C" void kernel_launch(void* const* d_in, const int* in_sizes, int n_in,
                              void* d_out, int out_size, void* d_ws, size_t ws_size,
                              hipStream_t stream) {
    const void* traj_rel = d_in[1];
    const void* h0   = d_in[2];
    const void* c0   = d_in[3];
    const void* W_ih = d_in[4];
    const void* W_hh = d_in[5];
    const void* b_ih = d_in[6];
    const void* b_hh = d_in[7];
    const void* W_se = d_in[8];
    const void* b_se = d_in[9];
    const void* W_pos  = d_in[10];
    const void* b_pos  = d_in[11];
    const void* W_conf = d_in[12];
    const void* b_conf = d_in[13];
    float* ws = (float*)d_ws;
    float* out = (float*)d_out;

    detect_kernel<<<1, 256, 0, stream>>>((const unsigned short*)W_hh,
                                         (int*)(ws + FLAG_IDX));
    prep_kernel<<<40, 256, 0, stream>>>(W_ih, W_hh, b_ih, b_hh, W_se, b_se,
                                        W_pos, b_pos, W_conf, b_conf, ws);
    lstm_kernel<<<BATCH / 32, 128, 0, stream>>>(traj_rel, h0, c0, ws, out);
}

// Round 3
// 207.867 us; speedup vs baseline: 1.5371x; 1.0028x over previous
//
#include <hip/hip_runtime.h>
#include <hip/hip_bf16.h>

typedef _Float16 half8 __attribute__((ext_vector_type(8)));
typedef _Float16 half4 __attribute__((ext_vector_type(4)));
typedef float float4v __attribute__((ext_vector_type(4)));

#define BATCH 32768
#define TT 30

#if __has_builtin(__builtin_amdgcn_exp2f)
#define FEXP2(x) __builtin_amdgcn_exp2f(x)
#else
#define FEXP2(x) __expf((x) * 0.6931471805599453f)
#endif
#if __has_builtin(__builtin_amdgcn_rcpf)
#define FRCP(x) __builtin_amdgcn_rcpf(x)
#else
#define FRCP(x) (1.0f / (x))
#endif

#define NLOG2E  -1.4426950408889634f
#define N2LOG2E -2.8853900817779268f

// ws offsets (floats). Gate weights/biases PRESCALED (-log2e; gate g -2log2e).
// 16x16x32 fragment layouts: A row=lane&15, k=(lane>>4)*8+j; B col=lane&15,
// same k; C/D col=lane&15, row=(lane>>4)*4+reg.
#define WFRAG_OFF 0        // f16[4 wv][4 gate][3 ks][64 lane][8] = 24576 halves
#define WCF_OFF   12288    // f16[2 role][2 ks][64 lane][8] = 2048 halves
#define BIASB_OFF 13312    // f32[256]  (b_ih + b_hh) * gate_scale
#define SXY_OFF   13568    // f32[16][3]   (Sx, Sy, bse)
#define CBIAS_OFF 13616    // f32[2][16]   (role0: bpos|0, role1: bx)
#define WCONF_OFF 13648    // f32[384]
#define BCONF_OFF 14032    // f32[6]
#define FLAG_IDX  14038    // int: 1 => inputs fp32, 0 => bf16
#define CONF_BASE (BATCH * 360)

__global__ void detect_kernel(const unsigned short* __restrict__ raw,
                              int* __restrict__ flag_out) {
    __shared__ int sflag[256];
    int local = 0;
    for (int i = threadIdx.x; i < 16384; i += 256) {
        unsigned short u = raw[i];
        if ((u & 0x7F80u) == 0x7F80u) local = 1;
    }
    sflag[threadIdx.x] = local;
    __syncthreads();
    if (threadIdx.x == 0) {
        int f = 0;
        for (int i = 0; i < 256; ++i) f |= sflag[i];
        flag_out[0] = f;
    }
}

__device__ __forceinline__ float ldin(const void* p, int i, int isf32) {
    return isf32 ? ((const float*)p)[i]
                 : (float)((const __hip_bfloat16*)p)[i];
}

__global__ void prep_kernel(const void* __restrict__ W_ih,
                            const void* __restrict__ W_hh,
                            const void* __restrict__ b_ih,
                            const void* __restrict__ b_hh,
                            const void* __restrict__ W_se,
                            const void* __restrict__ b_se,
                            const void* __restrict__ W_pos,
                            const void* __restrict__ b_pos,
                            const void* __restrict__ W_conf,
                            const void* __restrict__ b_conf,
                            float* __restrict__ ws)
{
    const int isf32 = ((const int*)(ws + FLAG_IDX))[0];
    int tid = blockIdx.x * blockDim.x + threadIdx.x;
    int stride = gridDim.x * blockDim.x;
    _Float16* wfh = (_Float16*)ws;

    // Gate-GEMM B fragments, 16x16x32 tiles, K padded to 96 (k>=80 -> 0).
    // wave wv owns units [16wv,16wv+16); row = gate*64 + wv*16 + col.
    for (int idx = tid; idx < 24576; idx += stride) {
        int jj = idx & 7, r = idx >> 3;
        int lane = r & 63; r >>= 6;
        int ks = r % 3; r /= 3;
        int gate = r & 3; int wv = r >> 2;
        int col = lane & 15, akq = lane >> 4;
        int k = ks * 32 + akq * 8 + jj;
        int row = gate * 64 + wv * 16 + col;
        float v = 0.f;
        if (k < 16) v = ldin(W_ih, row * 16 + k, isf32);
        else if (k < 80) v = ldin(W_hh, row * 64 + (k - 16), isf32);
        v *= (gate == 2) ? N2LOG2E : NLOG2E;
        wfh[idx] = (_Float16)v;
    }
    // Fused C-GEMM fragments: role0 cols = Wpos (rel), role1 cols = M=Wse*Wpos (x).
    _Float16* wch = (_Float16*)(ws + WCF_OFF);
    for (int idx = tid; idx < 2048; idx += stride) {
        int jj = idx & 7, r = idx >> 3;
        int lane = r & 63; r >>= 6;
        int ks = r & 1, role = r >> 1;
        int col = lane & 15, akq = lane >> 4;
        int k = ks * 32 + akq * 8 + jj;   // 0..63 over h
        float v = 0.f;
        if (role == 0) {
            if (col < 12) v = ldin(W_pos, col * 64 + k, isf32);
        } else {
            float s = 0.f;
            for (int p = 0; p < 12; ++p)
                s += ldin(W_se, col * 12 + p, isf32) * ldin(W_pos, p * 64 + k, isf32);
            v = s;
        }
        wch[idx] = (_Float16)v;
    }
    for (int idx = tid; idx < 256; idx += stride) {
        int gate = idx >> 6;
        float scale = (gate == 2) ? N2LOG2E : NLOG2E;
        ws[BIASB_OFF + idx] = (ldin(b_ih, idx, isf32) + ldin(b_hh, idx, isf32)) * scale;
    }
    for (int idx = tid; idx < 16; idx += stride) {
        float sx = 0.f, sy = 0.f;
        for (int m = 0; m < 6; ++m) {
            sx += ldin(W_se, idx * 12 + 2 * m, isf32);
            sy += ldin(W_se, idx * 12 + 2 * m + 1, isf32);
        }
        ws[SXY_OFF + idx * 3 + 0] = sx;
        ws[SXY_OFF + idx * 3 + 1] = sy;
        ws[SXY_OFF + idx * 3 + 2] = ldin(b_se, idx, isf32);
    }
    for (int idx = tid; idx < 32; idx += stride) {
        int w = idx >> 4, cc = idx & 15;
        float v = 0.f;
        if (w == 0) {
            if (cc < 12) v = ldin(b_pos, cc, isf32);
        } else {
            float s = ldin(b_se, cc, isf32);
            for (int p = 0; p < 12; ++p)
                s += ldin(W_se, cc * 12 + p, isf32) * ldin(b_pos, p, isf32);
            v = s;
        }
        ws[CBIAS_OFF + idx] = v;
    }
    for (int idx = tid; idx < 384; idx += stride)
        ws[WCONF_OFF + idx] = ldin(W_conf, idx, isf32);
    for (int idx = tid; idx < 6; idx += stride)
        ws[BCONF_OFF + idx] = ldin(b_conf, idx, isf32);
}

// block = 256 thr (4 waves), 32 agents in two 16-agent groups, phase-offset
// pipeline (3 barriers/step).  Wave wv owns hidden units [16wv,16wv+16) for
// gate GEMM + activations of BOTH groups; C-phase split: waves 0/1 -> C(G0)
// (rel | x), waves 2/3 -> C(G1).  Per-wave work halved vs the 2-wave version
// -> 4 independent issue streams per SIMD (16 waves/CU) to cover barrier +
// dependency stalls.
//   S1: A(G0,t) all | C(G1,t-1) wv2,3   -- bar
//   S2: A(G1,t) all | B(G0,t)   all     -- bar
//   S3: C(G0,t) wv0,1 | B(G1,t) all     -- bar
// zT per group: f16 [16 rows][104] (x16 | h64 | zero-pad16 | pad8).
__global__ __launch_bounds__(256, 4) void lstm_kernel(
    const void* __restrict__ traj_rel,
    const void* __restrict__ h0,
    const void* __restrict__ c0,
    const float* __restrict__ ws,
    float* __restrict__ out)
{
    __shared__ _Float16 zsh[2 * 16 * 104];
    __shared__ _Float16 predh[12 * 30 * 36];

    const int tid = threadIdx.x;
    const int lane = tid & 63;
    const int wid = __builtin_amdgcn_readfirstlane(tid >> 6);  // wave id 0..3
    const int role = wid & 1;           // C-phase role: 0=rel, 1=x
    const int col16 = lane & 15;
    const int akq = lane >> 4;          // 0..3
    const int base = blockIdx.x * 32;
    const int isf32 = ((const int*)(ws + FLAG_IDX))[0];

    // ---- per-lane constants ----
    const float4v* wfg = (const float4v*)ws;
    half8 Bf[4][3];
#pragma unroll
    for (int tl = 0; tl < 4; ++tl)
#pragma unroll
        for (int ks = 0; ks < 3; ++ks)
            Bf[tl][ks] = __builtin_bit_cast(half8,
                wfg[((wid * 4 + tl) * 3 + ks) * 64 + lane]);
    float bias4[4];
#pragma unroll
    for (int tl = 0; tl < 4; ++tl)
        bias4[tl] = ws[BIASB_OFF + tl * 64 + wid * 16 + col16];
    half8 wfc[2];
    {
        const float4v* wcg = (const float4v*)(ws + WCF_OFF);
#pragma unroll
        for (int ks = 0; ks < 2; ++ks)
            wfc[ks] = __builtin_bit_cast(half8, wcg[(role * 2 + ks) * 64 + lane]);
    }
    const float cb = ws[CBIAS_OFF + role * 16 + col16];

    // ---- init c (per group), unit = wid*16 + col16 ----
    float cg0[4], cg1[4];
    {
        int unit = wid * 16 + col16;
#pragma unroll
        for (int i = 0; i < 4; ++i) {
            cg0[i] = ldin(c0, (base + akq * 4 + i) * 64 + unit, isf32);
            cg1[i] = ldin(c0, (base + 16 + akq * 4 + i) * 64 + unit, isf32);
        }
    }
    // ---- init zT: h0, x0, zero-pad (256 threads) ----
    {
        int m = tid & 31, jq2 = tid >> 5;   // agent-in-block, col octile 0..7
        int g = m >> 4, row = m & 15;
        _Float16* zg = &zsh[g * 1664];
        half8 ha;
#pragma unroll
        for (int i = 0; i < 8; ++i)
            ha[i] = (_Float16)ldin(h0, (base + m) * 64 + jq2 * 8 + i, isf32);
        *(half8*)&zg[row * 104 + 16 + jq2 * 8] = ha;
        if (jq2 < 4) {
            float rx = ldin(traj_rel, 2 * (base + m), isf32);
            float ry = ldin(traj_rel, 2 * (base + m) + 1, isf32);
            half4 xs;
#pragma unroll
            for (int i = 0; i < 4; ++i) {
                int e = 4 * jq2 + i;
                float x = fmaf(rx, ws[SXY_OFF + e * 3],
                          fmaf(ry, ws[SXY_OFF + e * 3 + 1], ws[SXY_OFF + e * 3 + 2]));
                xs[i] = (_Float16)(x > 0.f ? x : 0.01f * x);
            }
            *(half4*)&zg[row * 104 + 4 * jq2] = xs;
        } else if (jq2 < 6) {   // zero-pad k = 80..95
            half8 zz = {};
            *(half8*)&zg[row * 104 + 80 + (jq2 - 4) * 8] = zz;
        }
    }
    __syncthreads();

    const int zbA = col16 * 104 + akq * 8;
    const int zbC = zbA + 16;
    const int hwb = 16 + wid * 16 + col16;   // h-write base

    float4v acc0[4], acc1[4];

#define ZG(g) (&zsh[(g) * 1664])

#define PHASE_A(G, ACC) do {                                                  \
    _Float16* zg_ = ZG(G);                                                    \
    _Pragma("unroll")                                                         \
    for (int tl = 0; tl < 4; ++tl) {                                          \
        float bv = bias4[tl];                                                 \
        ACC[tl][0] = bv; ACC[tl][1] = bv; ACC[tl][2] = bv; ACC[tl][3] = bv;   \
    }                                                                         \
    _Pragma("unroll")                                                         \
    for (int ks = 0; ks < 3; ++ks) {                                          \
        half8 af_ = *(const half8*)&zg_[zbA + ks * 32];                       \
        _Pragma("unroll")                                                     \
        for (int tl = 0; tl < 4; ++tl)                                        \
            ACC[tl] = __builtin_amdgcn_mfma_f32_16x16x32_f16(                 \
                af_, Bf[tl][ks], ACC[tl], 0, 0, 0);                           \
    }                                                                         \
} while (0)

#define PHASE_B(G, ACC, CARR) do {                                            \
    _Float16* zg_ = ZG(G);                                                    \
    _Pragma("unroll")                                                         \
    for (int i = 0; i < 4; ++i) {                                             \
        float si = FRCP(1.0f + FEXP2(ACC[0][i]));                             \
        float sf = FRCP(1.0f + FEXP2(ACC[1][i]));                             \
        float tg = fmaf(2.0f, FRCP(1.0f + FEXP2(ACC[2][i])), -1.0f);          \
        float so = FRCP(1.0f + FEXP2(ACC[3][i]));                             \
        float cn = fmaf(sf, CARR[i], si * tg);                                \
        CARR[i] = cn;                                                         \
        float th = fmaf(2.0f, FRCP(1.0f + FEXP2(cn * N2LOG2E)), -1.0f);       \
        float hn = so * th;                                                   \
        zg_[(akq * 4 + i) * 104 + hwb] = (_Float16)hn;                        \
    }                                                                         \
} while (0)

#define PHASE_C(G, T) do {                                                    \
    _Float16* zg_ = ZG(G);                                                    \
    float4v racc_;                                                            \
    racc_[0] = cb; racc_[1] = cb; racc_[2] = cb; racc_[3] = cb;               \
    _Pragma("unroll")                                                         \
    for (int ks = 0; ks < 2; ++ks) {                                          \
        half8 af_ = *(const half8*)&zg_[zbC + ks * 32];                       \
        racc_ = __builtin_amdgcn_mfma_f32_16x16x32_f16(                       \
            af_, wfc[ks], racc_, 0, 0, 0);                                    \
    }                                                                         \
    if (role == 0) {                                                          \
        if (col16 < 12) {                                                     \
            half4 hv_;                                                        \
            _Pragma("unroll")                                                 \
            for (int i = 0; i < 4; ++i) hv_[i] = (_Float16)racc_[i];          \
            *(half4*)&predh[(col16 * 30 + (T)) * 36 + (G) * 16 + akq * 4] = hv_; \
        }                                                                     \
    } else if ((T) != TT - 1) {                                               \
        _Pragma("unroll")                                                     \
        for (int i = 0; i < 4; ++i) {                                         \
            float xv_ = racc_[i];                                             \
            xv_ = xv_ > 0.f ? xv_ : 0.01f * xv_;                              \
            zg_[(akq * 4 + i) * 104 + col16] = (_Float16)xv_;                 \
        }                                                                     \
    }                                                                         \
} while (0)

    // ---- prologue (t = 0) ----
    PHASE_A(0, acc0);                                   // S1
    __syncthreads();
    PHASE_A(1, acc1); PHASE_B(0, acc0, cg0);            // S2
    __syncthreads();
    if (wid < 2) PHASE_C(0, 0);
    PHASE_B(1, acc1, cg1);                              // S3
    __syncthreads();

    for (int t = 1; t < TT; ++t) {
        PHASE_A(0, acc0);
        if (wid >= 2) PHASE_C(1, t - 1);                // S1
        __syncthreads();
        PHASE_A(1, acc1); PHASE_B(0, acc0, cg0);        // S2
        __syncthreads();
        if (wid < 2) PHASE_C(0, t);
        PHASE_B(1, acc1, cg1);                          // S3
        __syncthreads();
    }
    if (wid >= 2) PHASE_C(1, TT - 1);                   // epilogue
    __syncthreads();

    // ---- single coalesced flush: predh -> out ----
    {
        float4* po4 = (float4*)(out + (size_t)base * 360);
#pragma unroll 1
        for (int q2 = 0; q2 < 12; ++q2) {
            int idx4 = q2 * 256 + tid;
            if (idx4 < 2880) {
                int a = idx4 / 90, rem = idx4 % 90;
                int m = rem / 15, tq = rem % 15;
                int t0 = tq * 2;
                float4 o;
                o.x = (float)predh[((2 * m + 0) * 30 + t0) * 36 + a];
                o.y = (float)predh[((2 * m + 1) * 30 + t0) * 36 + a];
                o.z = (float)predh[((2 * m + 0) * 30 + t0 + 1) * 36 + a];
                o.w = (float)predh[((2 * m + 1) * 30 + t0 + 1) * 36 + a];
                po4[idx4] = o;
            }
        }
    }

    // ---- conf = softmax(h @ Wconf^T + bconf): wave 0, lanes 0..31 ----
    if (wid == 0 && lane < 32) {
        int m = lane;
        int g = m >> 4, row = m & 15;
        float l[6];
#pragma unroll
        for (int md = 0; md < 6; ++md) l[md] = ws[BCONF_OFF + md];
        for (int jj = 0; jj < 64; ++jj) {
            float hv = (float)zsh[g * 1664 + row * 104 + 16 + jj];
#pragma unroll
            for (int md = 0; md < 6; ++md)
                l[md] = fmaf(hv, ws[WCONF_OFF + md * 64 + jj], l[md]);
        }
        float mx = l[0];
#pragma unroll
        for (int md = 1; md < 6; ++md) mx = fmaxf(mx, l[md]);
        float ex[6], s = 0.f;
#pragma unroll
        for (int md = 0; md < 6; ++md) { ex[md] = __expf(l[md] - mx); s += ex[md]; }
        float inv = FRCP(s);
#pragma unroll
        for (int md = 0; md < 6; ++md)
            out[CONF_BASE + (size_t)(base + m) * 6 + md] = ex[md] * inv;
    }
}

extern "C" void kernel_launch(void* const* d_in, const int* in_sizes, int n_in,
                              void* d_out, int out_size, void* d_ws, size_t ws_size,
                              hipStream_t stream) {
    const void* traj_rel = d_in[1];
    const void* h0   = d_in[2];
    const void* c0   = d_in[3];
    const void* W_ih = d_in[4];
    const void* W_hh = d_in[5];
    const void* b_ih = d_in[6];
    const void* b_hh = d_in[7];
    const void* W_se = d_in[8];
    const void* b_se = d_in[9];
    const void* W_pos  = d_in[10];
    const void* b_pos  = d_in[11];
    const void* W_conf = d_in[12];
    const void* b_conf = d_in[13];
    float* ws = (float*)d_ws;
    float* out = (float*)d_out;

    detect_kernel<<<1, 256, 0, stream>>>((const unsigned short*)W_hh,
                                         (int*)(ws + FLAG_IDX));
    prep_kernel<<<40, 256, 0, stream>>>(W_ih, W_hh, b_ih, b_hh, W_se, b_se,
                                        W_pos, b_pos, W_conf, b_conf, ws);
    lstm_kernel<<<BATCH / 32, 256, 0, stream>>>(traj_rel, h0, c0, ws, out);
}

// Round 4
// 196.776 us; speedup vs baseline: 1.6238x; 1.0564x over previous
//
#include <hip/hip_runtime.h>
#include <hip/hip_bf16.h>

typedef _Float16 half8 __attribute__((ext_vector_type(8)));
typedef _Float16 half4 __attribute__((ext_vector_type(4)));
typedef float float4v __attribute__((ext_vector_type(4)));

#define BATCH 32768
#define TT 30

#if __has_builtin(__builtin_amdgcn_exp2f)
#define FEXP2(x) __builtin_amdgcn_exp2f(x)
#else
#define FEXP2(x) __expf((x) * 0.6931471805599453f)
#endif
#if __has_builtin(__builtin_amdgcn_rcpf)
#define FRCP(x) __builtin_amdgcn_rcpf(x)
#else
#define FRCP(x) (1.0f / (x))
#endif

#define NLOG2E  -1.4426950408889634f
#define N2LOG2E -2.8853900817779268f

// ws offsets (floats). Gate weights/biases PRESCALED (-log2e; gate g -2log2e).
// 16x16x32 fragment layouts: A row=lane&15, k=(lane>>4)*8+j; B col=lane&15,
// same k; C/D col=lane&15, row=(lane>>4)*4+reg.
#define WFRAG_OFF 0        // f16[4 wv][4 gate][3 ks][64 lane][8] = 24576 halves
#define WCF_OFF   12288    // f16[2 role][2 ks][64 lane][8] = 2048 halves
#define BIASB_OFF 13312    // f32[256]  (b_ih + b_hh) * gate_scale
#define SXY_OFF   13568    // f32[16][3]   (Sx, Sy, bse)
#define CBIAS_OFF 13616    // f32[2][16]   (role0: bpos|0, role1: bx)
#define WCONF_OFF 13648    // f32[384]
#define BCONF_OFF 14032    // f32[6]
#define FLAG_IDX  14038    // int: 1 => inputs fp32, 0 => bf16
#define CONF_BASE (BATCH * 360)

__global__ void detect_kernel(const unsigned short* __restrict__ raw,
                              int* __restrict__ flag_out) {
    __shared__ int sflag[256];
    int local = 0;
    for (int i = threadIdx.x; i < 16384; i += 256) {
        unsigned short u = raw[i];
        if ((u & 0x7F80u) == 0x7F80u) local = 1;
    }
    sflag[threadIdx.x] = local;
    __syncthreads();
    if (threadIdx.x == 0) {
        int f = 0;
        for (int i = 0; i < 256; ++i) f |= sflag[i];
        flag_out[0] = f;
    }
}

__device__ __forceinline__ float ldin(const void* p, int i, int isf32) {
    return isf32 ? ((const float*)p)[i]
                 : (float)((const __hip_bfloat16*)p)[i];
}

__global__ void prep_kernel(const void* __restrict__ W_ih,
                            const void* __restrict__ W_hh,
                            const void* __restrict__ b_ih,
                            const void* __restrict__ b_hh,
                            const void* __restrict__ W_se,
                            const void* __restrict__ b_se,
                            const void* __restrict__ W_pos,
                            const void* __restrict__ b_pos,
                            const void* __restrict__ W_conf,
                            const void* __restrict__ b_conf,
                            float* __restrict__ ws)
{
    const int isf32 = ((const int*)(ws + FLAG_IDX))[0];
    int tid = blockIdx.x * blockDim.x + threadIdx.x;
    int stride = gridDim.x * blockDim.x;
    _Float16* wfh = (_Float16*)ws;

    // Gate-GEMM B fragments, 16x16x32 tiles, K padded to 96 (k>=80 -> 0).
    // wave wv owns units [16wv,16wv+16); row = gate*64 + wv*16 + col.
    for (int idx = tid; idx < 24576; idx += stride) {
        int jj = idx & 7, r = idx >> 3;
        int lane = r & 63; r >>= 6;
        int ks = r % 3; r /= 3;
        int gate = r & 3; int wv = r >> 2;
        int col = lane & 15, akq = lane >> 4;
        int k = ks * 32 + akq * 8 + jj;
        int row = gate * 64 + wv * 16 + col;
        float v = 0.f;
        if (k < 16) v = ldin(W_ih, row * 16 + k, isf32);
        else if (k < 80) v = ldin(W_hh, row * 64 + (k - 16), isf32);
        v *= (gate == 2) ? N2LOG2E : NLOG2E;
        wfh[idx] = (_Float16)v;
    }
    // Fused C-GEMM fragments: role0 cols = Wpos (rel), role1 cols = M=Wse*Wpos (x).
    _Float16* wch = (_Float16*)(ws + WCF_OFF);
    for (int idx = tid; idx < 2048; idx += stride) {
        int jj = idx & 7, r = idx >> 3;
        int lane = r & 63; r >>= 6;
        int ks = r & 1, role = r >> 1;
        int col = lane & 15, akq = lane >> 4;
        int k = ks * 32 + akq * 8 + jj;   // 0..63 over h
        float v = 0.f;
        if (role == 0) {
            if (col < 12) v = ldin(W_pos, col * 64 + k, isf32);
        } else {
            float s = 0.f;
            for (int p = 0; p < 12; ++p)
                s += ldin(W_se, col * 12 + p, isf32) * ldin(W_pos, p * 64 + k, isf32);
            v = s;
        }
        wch[idx] = (_Float16)v;
    }
    for (int idx = tid; idx < 256; idx += stride) {
        int gate = idx >> 6;
        float scale = (gate == 2) ? N2LOG2E : NLOG2E;
        ws[BIASB_OFF + idx] = (ldin(b_ih, idx, isf32) + ldin(b_hh, idx, isf32)) * scale;
    }
    for (int idx = tid; idx < 16; idx += stride) {
        float sx = 0.f, sy = 0.f;
        for (int m = 0; m < 6; ++m) {
            sx += ldin(W_se, idx * 12 + 2 * m, isf32);
            sy += ldin(W_se, idx * 12 + 2 * m + 1, isf32);
        }
        ws[SXY_OFF + idx * 3 + 0] = sx;
        ws[SXY_OFF + idx * 3 + 1] = sy;
        ws[SXY_OFF + idx * 3 + 2] = ldin(b_se, idx, isf32);
    }
    for (int idx = tid; idx < 32; idx += stride) {
        int w = idx >> 4, cc = idx & 15;
        float v = 0.f;
        if (w == 0) {
            if (cc < 12) v = ldin(b_pos, cc, isf32);
        } else {
            float s = ldin(b_se, cc, isf32);
            for (int p = 0; p < 12; ++p)
                s += ldin(W_se, cc * 12 + p, isf32) * ldin(b_pos, p, isf32);
            v = s;
        }
        ws[CBIAS_OFF + idx] = v;
    }
    for (int idx = tid; idx < 384; idx += stride)
        ws[WCONF_OFF + idx] = ldin(W_conf, idx, isf32);
    for (int idx = tid; idx < 6; idx += stride)
        ws[BCONF_OFF + idx] = ldin(b_conf, idx, isf32);
}

// block = 256 thr (4 waves), 32 agents in two 16-agent groups.  h is parity
// DOUBLE-BUFFERED in LDS, so the A->B WAR hazard is gone and A(gates MFMA)
// + B(activations) of a group run back-to-back IN-WAVE in one slot.  Only
// 2 barriers/step:
//   S1: A+B(G0,t) all waves | C(G1,t-1) waves 2,3      -- bar
//   S2: A+B(G1,t) all waves | C(G0,t)   waves 0,1      -- bar
// z row layout per group (stride 168 halves, 16B-aligned, bank-clean b128):
//   [x 0..15 | zeropad 16..31 | h_par0 32..95 | h_par1 96..159 | spare]
// Activations use the common-denominator form: 5 exp2 + 2 rcp per cell
// (was 5+5).  Parity made compile-time by 2-step loop unroll.
__global__ __launch_bounds__(256, 4) void lstm_kernel(
    const void* __restrict__ traj_rel,
    const void* __restrict__ h0,
    const void* __restrict__ c0,
    const float* __restrict__ ws,
    float* __restrict__ out)
{
    __shared__ _Float16 zsh[2 * 16 * 168];
    __shared__ _Float16 predh[12 * 30 * 36];

    const int tid = threadIdx.x;
    const int lane = tid & 63;
    const int wid = __builtin_amdgcn_readfirstlane(tid >> 6);  // wave id 0..3
    const int role = wid & 1;           // C-phase role: 0=rel, 1=x
    const int col16 = lane & 15;
    const int akq = lane >> 4;          // 0..3
    const int base = blockIdx.x * 32;
    const int isf32 = ((const int*)(ws + FLAG_IDX))[0];

    // ---- per-lane constants ----
    const float4v* wfg = (const float4v*)ws;
    half8 Bf[4][3];
#pragma unroll
    for (int tl = 0; tl < 4; ++tl)
#pragma unroll
        for (int ks = 0; ks < 3; ++ks)
            Bf[tl][ks] = __builtin_bit_cast(half8,
                wfg[((wid * 4 + tl) * 3 + ks) * 64 + lane]);
    float bias4[4];
#pragma unroll
    for (int tl = 0; tl < 4; ++tl)
        bias4[tl] = ws[BIASB_OFF + tl * 64 + wid * 16 + col16];
    half8 wfc[2];
    {
        const float4v* wcg = (const float4v*)(ws + WCF_OFF);
#pragma unroll
        for (int ks = 0; ks < 2; ++ks)
            wfc[ks] = __builtin_bit_cast(half8, wcg[(role * 2 + ks) * 64 + lane]);
    }
    const float cb = ws[CBIAS_OFF + role * 16 + col16];

    // ---- precomputed LDS addresses (halves) ----
    int aoff[2][3];   // A-read base per parity per ks (chunk-mapped)
#pragma unroll
    for (int p = 0; p < 2; ++p)
#pragma unroll
        for (int ks = 0; ks < 3; ++ks) {
            int q = ks * 4 + akq;          // global k-chunk 0..11
            int off = (q < 2) ? q * 8
                    : (q < 10) ? 32 + p * 64 + (q - 2) * 8
                               : 16 + (q - 10) * 8;
            aoff[p][ks] = col16 * 168 + off;
        }
    const int zcb = col16 * 168 + 32 + akq * 8;  // C h-read (+P*64 +ks*32)
    const int rb = akq * 672;                    // row base (akq*4)*168
    const int hb = 32 + wid * 16 + col16;        // h-write (+i*168 +PN*64)

    // ---- init c (per group), unit = wid*16 + col16 ----
    float cg0[4], cg1[4];
    {
        int unit = wid * 16 + col16;
#pragma unroll
        for (int i = 0; i < 4; ++i) {
            cg0[i] = ldin(c0, (base + akq * 4 + i) * 64 + unit, isf32);
            cg1[i] = ldin(c0, (base + 16 + akq * 4 + i) * 64 + unit, isf32);
        }
    }
    // ---- init z: h0 -> par0, x0, zero-pad (256 threads) ----
    {
        int m = tid & 31, jq2 = tid >> 5;   // agent-in-block, octile 0..7
        int g = m >> 4, row = m & 15;
        _Float16* zg = &zsh[g * 2688 + row * 168];
        half8 ha;
#pragma unroll
        for (int i = 0; i < 8; ++i)
            ha[i] = (_Float16)ldin(h0, (base + m) * 64 + jq2 * 8 + i, isf32);
        *(half8*)&zg[32 + jq2 * 8] = ha;
        if (jq2 < 4) {
            float rx = ldin(traj_rel, 2 * (base + m), isf32);
            float ry = ldin(traj_rel, 2 * (base + m) + 1, isf32);
            half4 xs;
#pragma unroll
            for (int i = 0; i < 4; ++i) {
                int e = 4 * jq2 + i;
                float x = fmaf(rx, ws[SXY_OFF + e * 3],
                          fmaf(ry, ws[SXY_OFF + e * 3 + 1], ws[SXY_OFF + e * 3 + 2]));
                xs[i] = (_Float16)(x > 0.f ? x : 0.01f * x);
            }
            *(half4*)&zg[4 * jq2] = xs;
        } else if (jq2 < 6) {   // zero-pad chunks (k = 80..95)
            half8 zz = {};
            *(half8*)&zg[16 + (jq2 - 4) * 8] = zz;
        }
    }
    __syncthreads();

    _Float16* const zg0p = &zsh[0];
    _Float16* const zg1p = &zsh[2688];

#define PHASE_AB(ZG, PC, PN, CARR) do {                                       \
    float4v acc_[4];                                                          \
    _Pragma("unroll")                                                         \
    for (int tl = 0; tl < 4; ++tl) {                                          \
        float bv = bias4[tl];                                                 \
        acc_[tl][0] = bv; acc_[tl][1] = bv; acc_[tl][2] = bv; acc_[tl][3] = bv;\
    }                                                                         \
    _Pragma("unroll")                                                         \
    for (int ks = 0; ks < 3; ++ks) {                                          \
        half8 af_ = *(const half8*)&(ZG)[aoff[PC][ks]];                       \
        _Pragma("unroll")                                                     \
        for (int tl = 0; tl < 4; ++tl)                                        \
            acc_[tl] = __builtin_amdgcn_mfma_f32_16x16x32_f16(                \
                af_, Bf[tl][ks], acc_[tl], 0, 0, 0);                          \
    }                                                                         \
    _Pragma("unroll")                                                         \
    for (int i = 0; i < 4; ++i) {                                             \
        float ei = FEXP2(acc_[0][i]);                                         \
        float ef = FEXP2(acc_[1][i]);                                         \
        float eg = FEXP2(acc_[2][i]);                                         \
        float eo = FEXP2(acc_[3][i]);                                         \
        float pp = (1.f + ei) * (1.f + eg);                                   \
        float qq = 1.f + ef;                                                  \
        float cn = fmaf((CARR)[i], pp, (1.f - eg) * qq) * FRCP(pp * qq);      \
        (CARR)[i] = cn;                                                       \
        float ec = FEXP2(cn * N2LOG2E);                                       \
        float hn = (1.f - ec) * FRCP((1.f + eo) * (1.f + ec));                \
        (ZG)[rb + i * 168 + (PN) * 64 + hb] = (_Float16)hn;                   \
    }                                                                         \
} while (0)

#define PHASE_C(ZG, P, T, GI) do {                                            \
    float4v racc_;                                                            \
    racc_[0] = cb; racc_[1] = cb; racc_[2] = cb; racc_[3] = cb;               \
    _Pragma("unroll")                                                         \
    for (int ks = 0; ks < 2; ++ks) {                                          \
        half8 af_ = *(const half8*)&(ZG)[zcb + (P) * 64 + ks * 32];           \
        racc_ = __builtin_amdgcn_mfma_f32_16x16x32_f16(                       \
            af_, wfc[ks], racc_, 0, 0, 0);                                    \
    }                                                                         \
    if (role == 0) {                                                          \
        if (col16 < 12) {                                                     \
            half4 hv_;                                                        \
            _Pragma("unroll")                                                 \
            for (int i = 0; i < 4; ++i) hv_[i] = (_Float16)racc_[i];          \
            *(half4*)&predh[(col16 * 30 + (T)) * 36 + (GI) * 16 + akq * 4] = hv_;\
        }                                                                     \
    } else if ((T) != TT - 1) {                                               \
        _Pragma("unroll")                                                     \
        for (int i = 0; i < 4; ++i) {                                         \
            float xv_ = racc_[i];                                             \
            xv_ = xv_ > 0.f ? xv_ : 0.01f * xv_;                              \
            (ZG)[rb + i * 168 + col16] = (_Float16)xv_;                       \
        }                                                                     \
    }                                                                         \
} while (0)

    // ---- prologue: t = 0 (parity: read 0, write 1) ----
    PHASE_AB(zg0p, 0, 1, cg0);                       // S1_0
    __syncthreads();
    PHASE_AB(zg1p, 0, 1, cg1);
    if (wid < 2) PHASE_C(zg0p, 1, 0, 0);             // S2_0
    __syncthreads();

    // ---- main loop, 2 steps per iteration (compile-time parity) ----
    for (int t = 1; t < TT - 1; t += 2) {
        // step t (odd): pc=1, pn=0
        PHASE_AB(zg0p, 1, 0, cg0);
        if (wid >= 2) PHASE_C(zg1p, 1, t - 1, 1);    // S1
        __syncthreads();
        PHASE_AB(zg1p, 1, 0, cg1);
        if (wid < 2) PHASE_C(zg0p, 0, t, 0);         // S2
        __syncthreads();
        // step t+1 (even): pc=0, pn=1
        PHASE_AB(zg0p, 0, 1, cg0);
        if (wid >= 2) PHASE_C(zg1p, 0, t, 1);        // S1
        __syncthreads();
        PHASE_AB(zg1p, 0, 1, cg1);
        if (wid < 2) PHASE_C(zg0p, 1, t + 1, 0);     // S2
        __syncthreads();
    }
    // ---- tail: t = 29 (odd) ----
    PHASE_AB(zg0p, 1, 0, cg0);
    if (wid >= 2) PHASE_C(zg1p, 1, TT - 2, 1);       // S1: C(G1,28)
    __syncthreads();
    PHASE_AB(zg1p, 1, 0, cg1);
    if (wid < 2) PHASE_C(zg0p, 0, TT - 1, 0);        // S2: C(G0,29)
    __syncthreads();
    if (wid >= 2) PHASE_C(zg1p, 0, TT - 1, 1);       // epilogue: C(G1,29)
    __syncthreads();

    // ---- single coalesced flush: predh -> out ----
    {
        float4* po4 = (float4*)(out + (size_t)base * 360);
#pragma unroll 1
        for (int q2 = 0; q2 < 12; ++q2) {
            int idx4 = q2 * 256 + tid;
            if (idx4 < 2880) {
                int a = idx4 / 90, rem = idx4 % 90;
                int m = rem / 15, tq = rem % 15;
                int t0 = tq * 2;
                float4 o;
                o.x = (float)predh[((2 * m + 0) * 30 + t0) * 36 + a];
                o.y = (float)predh[((2 * m + 1) * 30 + t0) * 36 + a];
                o.z = (float)predh[((2 * m + 0) * 30 + t0 + 1) * 36 + a];
                o.w = (float)predh[((2 * m + 1) * 30 + t0 + 1) * 36 + a];
                po4[idx4] = o;
            }
        }
    }

    // ---- conf = softmax(h @ Wconf^T + bconf): wave 0, lanes 0..31 ----
    // final h = h_30 lives in parity 0 (offset 32)
    if (wid == 0 && lane < 32) {
        int m = lane;
        int g = m >> 4, row = m & 15;
        float l[6];
#pragma unroll
        for (int md = 0; md < 6; ++md) l[md] = ws[BCONF_OFF + md];
        for (int jj = 0; jj < 64; ++jj) {
            float hv = (float)zsh[g * 2688 + row * 168 + 32 + jj];
#pragma unroll
            for (int md = 0; md < 6; ++md)
                l[md] = fmaf(hv, ws[WCONF_OFF + md * 64 + jj], l[md]);
        }
        float mx = l[0];
#pragma unroll
        for (int md = 1; md < 6; ++md) mx = fmaxf(mx, l[md]);
        float ex[6], s = 0.f;
#pragma unroll
        for (int md = 0; md < 6; ++md) { ex[md] = __expf(l[md] - mx); s += ex[md]; }
        float inv = FRCP(s);
#pragma unroll
        for (int md = 0; md < 6; ++md)
            out[CONF_BASE + (size_t)(base + m) * 6 + md] = ex[md] * inv;
    }
}

extern "C" void kernel_launch(void* const* d_in, const int* in_sizes, int n_in,
                              void* d_out, int out_size, void* d_ws, size_t ws_size,
                              hipStream_t stream) {
    const void* traj_rel = d_in[1];
    const void* h0   = d_in[2];
    const void* c0   = d_in[3];
    const void* W_ih = d_in[4];
    const void* W_hh = d_in[5];
    const void* b_ih = d_in[6];
    const void* b_hh = d_in[7];
    const void* W_se = d_in[8];
    const void* b_se = d_in[9];
    const void* W_pos  = d_in[10];
    const void* b_pos  = d_in[11];
    const void* W_conf = d_in[12];
    const void* b_conf = d_in[13];
    float* ws = (float*)d_ws;
    float* out = (float*)d_out;

    detect_kernel<<<1, 256, 0, stream>>>((const unsigned short*)W_hh,
                                         (int*)(ws + FLAG_IDX));
    prep_kernel<<<40, 256, 0, stream>>>(W_ih, W_hh, b_ih, b_hh, W_se, b_se,
                                        W_pos, b_pos, W_conf, b_conf, ws);
    lstm_kernel<<<BATCH / 32, 256, 0, stream>>>(traj_rel, h0, c0, ws, out);
}